// Round 1
// baseline (401.939 us; speedup 1.0000x reference)
//
#include <hip/hip_runtime.h>
#include <math.h>

// ---------------- geometry / problem constants ----------------
#define L2C 25          // (LMAX+1)^2 spherical slots
#define CH  128         // channels
#define NB  2           // nodes per block
#define GLB 7           // Gauss-Legendre beta nodes (exact: band-12 poly needs 2n-1>=12 -> n=7)
#define GLA 13          // uniform alpha nodes (exact for |k|<=12)
#define NG  (GLB*GLA)   // 91 grid points (vs reference 342 -- mathematically identical projection)
#define TSTRIDE 50      // per-grid-point table row: 25 TO + 25 FROM
#define TAB_FLOATS 4608 // >= NG*TSTRIDE (4550), keeps following ws blocks 16B-aligned
#define WT_FLOATS (5*CH*CH)

// degree of each (l,m) slot
constexpr int LIDX[L2C] = {0,1,1,1,2,2,2,2,2,3,3,3,3,3,3,3,4,4,4,4,4,4,4,4,4};

// ---------------- build SH tables on device (graph-capture safe, deterministic) ----------------
__global__ void build_tables_kernel(float* __restrict__ tab) {
  const int g = blockIdx.x * blockDim.x + threadIdx.x;
  if (g >= NG) return;
  const int b = g / GLA;
  const int a = g % GLA;
  const double PI = 3.14159265358979323846;

  // Newton solve for Gauss-Legendre node b of P_GLB (double precision)
  double xx = cos(PI * (b + 0.75) / (GLB + 0.5));
  double pp = 1.0;
  for (int it = 0; it < 64; ++it) {
    double p0 = 1.0, p1 = xx;
    for (int j = 2; j <= GLB; ++j) {
      double p2 = ((2.0*j - 1.0)*xx*p1 - (j - 1.0)*p0) / j;
      p0 = p1; p1 = p2;
    }
    pp = GLB * (xx*p1 - p0) / (xx*xx - 1.0);
    xx -= p1 / pp;
  }
  { // final derivative at converged node
    double p0 = 1.0, p1 = xx;
    for (int j = 2; j <= GLB; ++j) {
      double p2 = ((2.0*j - 1.0)*xx*p1 - (j - 1.0)*p0) / j;
      p0 = p1; p1 = p2;
    }
    pp = GLB * (xx*p1 - p0) / (xx*xx - 1.0);
  }
  const double wb = 2.0 / ((1.0 - xx*xx) * pp * pp);
  const double ct = xx;
  const double sx = sqrt(fmax(0.0, 1.0 - ct*ct));

  // associated Legendre with Condon-Shortley phase (matches reference recurrences)
  double P[5][5];
  P[0][0] = 1.0;
  for (int m = 1; m <= 4; ++m) P[m][m] = -(2.0*m - 1.0) * sx * P[m-1][m-1];
  for (int m = 0; m <= 3; ++m) P[m+1][m] = (2.0*m + 1.0) * ct * P[m][m];
  for (int m = 0; m <= 4; ++m)
    for (int l = m + 2; l <= 4; ++l)
      P[l][m] = ((2.0*l - 1.0)*ct*P[l-1][m] - (l + m - 1.0)*P[l-2][m]) / (l - m);

  const double fact[9] = {1,1,2,6,24,120,720,5040,40320};
  const double phi = (2.0*PI/GLA) * a;
  double Y[L2C];
  for (int l = 0; l <= 4; ++l) {
    for (int m = 0; m <= l; ++m) {
      double Nlm = sqrt((2.0*l + 1.0) / (4.0*PI) * fact[l-m] / fact[l+m]);
      if (m == 0) {
        Y[l*l + l] = Nlm * P[l][0];
      } else {
        double base = sqrt(2.0) * Nlm * P[l][m];
        Y[l*l + l + m] = base * cos((double)m * phi);
        Y[l*l + l - m] = base * sin((double)m * phi);
      }
    }
  }
  const double wg = wb * (2.0*PI/GLA);
  for (int s = 0; s < L2C; ++s) {
    tab[g*TSTRIDE + s]       = (float)Y[s];         // TO row
    tab[g*TSTRIDE + 25 + s]  = (float)(wg * Y[s]);  // FROM row (quadrature-weighted)
  }
}

// ---------------- transpose weights: w[d][k][c] -> wt[d][c][k] (k-coalesced inner loop) ---------
__global__ void transpose_w_kernel(const float* __restrict__ w, float* __restrict__ wt) {
  const int i = blockIdx.x * 256 + threadIdx.x;
  if (i >= WT_FLOATS) return;
  const int d   = i >> 14;
  const int rem = i & 16383;
  const int cin = rem >> 7;
  const int k   = rem & 127;
  wt[i] = w[(d << 14) | (k << 7) | cin];
}

// ---------------- fused main kernel: LN -> linear1 -> gaunt -> linear2 -> +res -----------------
__global__ __launch_bounds__(256) void eqv3_fused_kernel(
    const float* __restrict__ x,
    const float* __restrict__ norm_w, const float* __restrict__ norm_b,
    const float* __restrict__ w1t, const float* __restrict__ b1,
    const float* __restrict__ w_tp,
    const float* __restrict__ w2t, const float* __restrict__ b2,
    const float* __restrict__ tab,
    float* __restrict__ out)
{
  __shared__ __align__(16) float h[NB][L2C][CH];
  __shared__ float red[4];
  __shared__ float stat[NB][2];   // [node][0]=mean0, [1]=rstd

  const int tid  = threadIdx.x;
  const int nb   = tid >> 7;      // node within block (0..1)
  const int c    = tid & 127;     // channel (and k index for linears)
  const int lane = tid & 63;
  const int wid  = tid >> 6;      // waves 0,1 -> node 0; waves 2,3 -> node 1
  const long n0  = (long)blockIdx.x * NB;
  const float* xblk = x + n0 * (L2C*CH);

  // ---- stage x into LDS (coalesced float4) ----
  {
    const float4* src = (const float4*)xblk;
    float4* dst = (float4*)&h[0][0][0];
    for (int i = tid; i < NB*L2C*CH/4; i += 256) dst[i] = src[i];
  }
  __syncthreads();

  // ---- mean of l=0 row, per node ----
  {
    float v = h[nb][0][c];
    #pragma unroll
    for (int o = 32; o > 0; o >>= 1) v += __shfl_down(v, o, 64);
    if (lane == 0) red[wid] = v;
  }
  __syncthreads();
  if (tid == 0) {
    stat[0][0] = (red[0] + red[1]) * (1.0f/CH);
    stat[1][0] = (red[2] + red[3]) * (1.0f/CH);
  }
  __syncthreads();
  h[nb][0][c] -= stat[nb][0];
  __syncthreads();

  // ---- variance over all L2C*CH centered values, per node ----
  {
    float s = 0.f;
    const float* hb = &h[nb][0][0];
    for (int j = c; j < L2C*CH; j += CH) { float u = hb[j]; s += u*u; }
    #pragma unroll
    for (int o = 32; o > 0; o >>= 1) s += __shfl_down(s, o, 64);
    if (lane == 0) red[wid] = s;
  }
  __syncthreads();
  if (tid == 0) {
    stat[0][1] = rsqrtf((red[0] + red[1]) * (1.0f/(L2C*CH)) + 1e-5f);
    stat[1][1] = rsqrtf((red[2] + red[3]) * (1.0f/(L2C*CH)) + 1e-5f);
  }
  __syncthreads();

  // ---- normalize + per-(degree,channel) affine; bias on l=0 only ----
  {
    const float rs = stat[nb][1];
    float nw[5];
    #pragma unroll
    for (int d = 0; d < 5; ++d) nw[d] = norm_w[d*CH + c] * rs;
    const float bb = norm_b[c];
    #pragma unroll
    for (int l = 0; l < L2C; ++l) {
      float val = h[nb][l][c] * nw[LIDX[l]];
      if (l == 0) val += bb;
      h[nb][l][c] = val;
    }
  }
  __syncthreads();

  // ---- per-degree linear: thread owns output column k=c for all 25 slots of its node ----
  // y[l,k] = sum_c h[l,c] * wt[LIDX[l]][c][k]; only 5 weight loads per c-step (degree sharing)
  float acc[L2C];
  auto so3_linear = [&](const float* __restrict__ wt, const float* __restrict__ bias) {
    #pragma unroll
    for (int l = 0; l < L2C; ++l) acc[l] = 0.f;
    acc[0] = bias[c];
    for (int cc = 0; cc < CH; cc += 4) {
      float wv[5][4];
      #pragma unroll
      for (int d = 0; d < 5; ++d) {
        const float* wp = wt + ((d*CH + cc)*CH + c);
        #pragma unroll
        for (int j = 0; j < 4; ++j) wv[d][j] = wp[j*CH];
      }
      #pragma unroll
      for (int l = 0; l < L2C; ++l) {
        const float4 hv = *(const float4*)&h[nb][l][cc];  // wave-uniform LDS broadcast
        const int d = LIDX[l];
        acc[l] += hv.x*wv[d][0] + hv.y*wv[d][1] + hv.z*wv[d][2] + hv.w*wv[d][3];
      }
    }
  };

  so3_linear(w1t, b1);
  __syncthreads();                 // all h reads done before overwrite
  #pragma unroll
  for (int l = 0; l < L2C; ++l) h[nb][l][c] = acc[l];
  __syncthreads();

  // ---- Gaunt self-TP: fully per-(node,channel) in registers; tables are wave-uniform loads ----
  {
    float hreg[L2C];
    #pragma unroll
    for (int l = 0; l < L2C; ++l) hreg[l] = h[nb][l][c];
    __syncthreads();               // reads complete before anyone writes h below
    float a2[L2C];
    #pragma unroll
    for (int l = 0; l < L2C; ++l) a2[l] = 0.f;
    for (int g = 0; g < NG; ++g) {
      const float* tr = tab + g*TSTRIDE;
      float t = 0.f;
      #pragma unroll
      for (int l = 0; l < L2C; ++l) t += tr[l] * hreg[l];     // to-grid
      const float t2 = t * t;                                  // pointwise square
      #pragma unroll
      for (int l = 0; l < L2C; ++l) a2[l] += tr[25+l] * t2;    // projection
    }
    float wt5[5];
    #pragma unroll
    for (int d = 0; d < 5; ++d) wt5[d] = w_tp[d*CH + c];
    #pragma unroll
    for (int l = 0; l < L2C; ++l) h[nb][l][c] = a2[l] * wt5[LIDX[l]];
  }
  __syncthreads();

  // ---- second linear + bias(l=0) + residual, write out (coalesced) ----
  so3_linear(w2t, b2);
  {
    float* op = out + n0 * (L2C*CH);
    #pragma unroll
    for (int l = 0; l < L2C; ++l) {
      const int idx = (nb*L2C + l)*CH + c;
      op[idx] = acc[l] + xblk[idx];
    }
  }
}

// ---------------- launch ----------------
extern "C" void kernel_launch(void* const* d_in, const int* in_sizes, int n_in,
                              void* d_out, int out_size, void* d_ws, size_t ws_size,
                              hipStream_t stream) {
  const float* x      = (const float*)d_in[0];
  // d_in[1] = batch (unused by reference)
  const float* norm_w = (const float*)d_in[2];
  const float* norm_b = (const float*)d_in[3];
  const float* w1     = (const float*)d_in[4];
  const float* b1     = (const float*)d_in[5];
  const float* w_tp   = (const float*)d_in[6];
  const float* w2     = (const float*)d_in[7];
  const float* b2     = (const float*)d_in[8];
  float* out = (float*)d_out;

  const int N = in_sizes[0] / (L2C*CH);   // 6000

  float* ws  = (float*)d_ws;              // needs (4608 + 2*81920)*4 ~= 674 KB
  float* tab = ws;
  float* w1t = ws + TAB_FLOATS;
  float* w2t = w1t + WT_FLOATS;

  build_tables_kernel<<<1, 128, 0, stream>>>(tab);
  transpose_w_kernel<<<(WT_FLOATS + 255)/256, 256, 0, stream>>>(w1, w1t);
  transpose_w_kernel<<<(WT_FLOATS + 255)/256, 256, 0, stream>>>(w2, w2t);
  eqv3_fused_kernel<<<N/NB, 256, 0, stream>>>(x, norm_w, norm_b, w1t, b1, w_tp, w2t, b2, tab, out);
}

// Round 2
// 129.311 us; speedup vs baseline: 3.1083x; 3.1083x over previous
//
#include <hip/hip_runtime.h>
#include <math.h>

// ---------------- constants ----------------
#define L2C 25
#define CH  128
#define NB  8           // nodes per block
#define GLB 7           // Gauss-Legendre beta nodes (band-12 exact)
#define GLA 13          // uniform alpha nodes (exact |k|<=12)
#define NG  91          // 7*13 grid points (mathematically identical to ref 342)
#define GPAD 96
#define KPAD 32
#define ROWS 240        // degree-grouped (slot,node) rows padded to 16

typedef short bf16x8 __attribute__((ext_vector_type(8)));
typedef short short4v __attribute__((ext_vector_type(4)));
typedef float f32x4 __attribute__((ext_vector_type(4)));

__device__ inline short f2bf(float f) {
  union { float f; unsigned u; } v; v.f = f;
  unsigned r = (v.u + 0x7FFFu + ((v.u >> 16) & 1u)) >> 16;
  return (short)r;
}

// ---------------- SH tables (bf16), built on device ----------------
__global__ void build_tables_kernel(short* __restrict__ toT, short* __restrict__ frT) {
  const int t = threadIdx.x;
  if (t >= GPAD) return;
  const int g = t;
  const double PI = 3.14159265358979323846;
  double Y[L2C];
  double wg = 0.0;
  if (g < NG) {
    const int b = g / GLA;
    const int a = g % GLA;
    // Newton solve for GL node b of P_GLB
    double xx = cos(PI * (b + 0.75) / (GLB + 0.5));
    double pp = 1.0;
    for (int it = 0; it < 64; ++it) {
      double p0 = 1.0, p1 = xx;
      for (int j = 2; j <= GLB; ++j) { double p2 = ((2.0*j-1.0)*xx*p1 - (j-1.0)*p0)/j; p0 = p1; p1 = p2; }
      pp = GLB * (xx*p1 - p0) / (xx*xx - 1.0);
      xx -= p1 / pp;
    }
    { double p0 = 1.0, p1 = xx;
      for (int j = 2; j <= GLB; ++j) { double p2 = ((2.0*j-1.0)*xx*p1 - (j-1.0)*p0)/j; p0 = p1; p1 = p2; }
      pp = GLB * (xx*p1 - p0) / (xx*xx - 1.0); }
    const double wb = 2.0 / ((1.0 - xx*xx) * pp * pp);
    const double ct = xx;
    const double sx = sqrt(fmax(0.0, 1.0 - ct*ct));
    double P[5][5];
    P[0][0] = 1.0;
    for (int m = 1; m <= 4; ++m) P[m][m] = -(2.0*m - 1.0) * sx * P[m-1][m-1];
    for (int m = 0; m <= 3; ++m) P[m+1][m] = (2.0*m + 1.0) * ct * P[m][m];
    for (int m = 0; m <= 4; ++m)
      for (int l = m + 2; l <= 4; ++l)
        P[l][m] = ((2.0*l-1.0)*ct*P[l-1][m] - (l+m-1.0)*P[l-2][m]) / (l - m);
    const double fact[9] = {1,1,2,6,24,120,720,5040,40320};
    const double phi = (2.0*PI/GLA) * a;
    for (int l = 0; l <= 4; ++l)
      for (int m = 0; m <= l; ++m) {
        double Nlm = sqrt((2.0*l+1.0)/(4.0*PI) * fact[l-m]/fact[l+m]);
        if (m == 0) Y[l*l + l] = Nlm * P[l][0];
        else {
          double base = sqrt(2.0) * Nlm * P[l][m];
          Y[l*l + l + m] = base * cos((double)m * phi);
          Y[l*l + l - m] = base * sin((double)m * phi);
        }
      }
    wg = wb * (2.0*PI/GLA);
  }
  for (int l = 0; l < KPAD; ++l) {
    float tv = (g < NG && l < L2C) ? (float)Y[l] : 0.f;
    toT[g*KPAD + l] = f2bf(tv);
  }
  for (int l = 0; l < KPAD; ++l) {
    float fv = (g < NG && l < L2C) ? (float)(wg * Y[l]) : 0.f;
    frT[l*GPAD + g] = f2bf(fv);
  }
}

// ---------------- fp32 -> bf16 weight conversion ----------------
__global__ void convert_w_kernel(const float* __restrict__ w1, const float* __restrict__ w2,
                                 short* __restrict__ wb1, short* __restrict__ wb2) {
  const int i = blockIdx.x * 256 + threadIdx.x;
  if (i < 5*CH*CH) { wb1[i] = f2bf(w1[i]); wb2[i] = f2bf(w2[i]); }
}

// ---------------- fused main kernel ----------------
__global__ __launch_bounds__(512, 1) void eqv3_mfma_kernel(
    const float* __restrict__ x,
    const float* __restrict__ norm_w, const float* __restrict__ norm_b,
    const short* __restrict__ wb1, const float* __restrict__ b1,
    const float* __restrict__ w_tp,
    const short* __restrict__ wb2, const float* __restrict__ b2,
    const short* __restrict__ toT, const short* __restrict__ frT,
    float* __restrict__ out)
{
  // chunk-of-8 (16B) major layouts: every MFMA fragment access is 16B-contiguous across 16 lanes
  __shared__ __align__(16) short hsh[16][242][8];      // h: [c-chunk][row(slot,node)+pad][8]  61952 B
  __shared__ __align__(16) short hg[NB][4][CH][8];     // linear1 out: [node][l-chunk][c][8]   65536 B
  __shared__ __align__(16) short g2[12][CH][8];        // grid^2:      [g-chunk][c][8]         24576 B

  const int tid  = threadIdx.x;
  const int w    = tid >> 6;     // wave id = N-tile / c-tile / LN-node
  const int lane = tid & 63;
  const int l16  = lane & 15;
  const int lq   = lane >> 4;
  const long n0  = (long)blockIdx.x * NB;

  constexpr int LDEG[L2C] = {0,1,1,1,2,2,2,2,2,3,3,3,3,3,3,3,4,4,4,4,4,4,4,4,4};
  constexpr int BROW[5]   = {0,16,48,96,160};

  // ---- zero hg pad l-slots 25..31 (wave-private k-columns; NaN-safety for MFMA) ----
  for (int i = lane; i < 8*16*7; i += 64) {
    const int node = i / (16*7);
    const int r    = i % (16*7);
    const int k    = w*16 + r / 7;
    const int l    = 25 + r % 7;
    hg[node][3][k][l & 7] = 0;
  }

  // ---- LayerNorm: wave w owns node w ----
  {
    const float* xn = x + (n0 + w) * (L2C*CH);
    const float2* x2 = (const float2*)xn;
    float s0 = 0.f, s0q = 0.f, sq = 0.f;
    for (int j = lane; j < L2C*CH/2; j += 64) {
      const float2 v = x2[j];
      const float t = v.x*v.x + v.y*v.y;
      if (j < 64) { s0 += v.x + v.y; s0q += t; }   // slot-0 row (wave-uniform branch)
      else        sq += t;
    }
    #pragma unroll
    for (int o = 1; o < 64; o <<= 1) {
      s0  += __shfl_xor(s0,  o, 64);
      s0q += __shfl_xor(s0q, o, 64);
      sq  += __shfl_xor(sq,  o, 64);
    }
    const float mean0 = s0 * (1.f/CH);
    const float var   = (sq + s0q - CH*mean0*mean0) * (1.f/(L2C*CH));
    const float rstd  = rsqrtf(var + 1e-5f);
    #pragma unroll
    for (int s = 0; s < L2C; ++s) {
      const int d   = LDEG[s];
      const int row = BROW[d] + (s - d*d)*NB + w;
      const float2 v = x2[s*64 + lane];
      const int c0 = 2*lane;
      float a0 = v.x, a1 = v.y;
      if (s == 0) { a0 -= mean0; a1 -= mean0; }
      a0 *= rstd * norm_w[d*CH + c0];
      a1 *= rstd * norm_w[d*CH + c0 + 1];
      if (s == 0) { a0 += norm_b[c0]; a1 += norm_b[c0+1]; }
      const unsigned pk = (unsigned)(unsigned short)f2bf(a0) | ((unsigned)(unsigned short)f2bf(a1) << 16);
      *(unsigned*)&hsh[c0 >> 3][row][c0 & 7] = pk;
    }
  }
  __syncthreads();

  // ---- linear1: y = h x W1^T per degree; output -> hg[node][l-chunk][k][l&7] (wave-private k) ----
  {
    const int k = w*16 + l16;
    #pragma unroll
    for (int d = 0; d < 5; ++d) {
      bf16x8 B[4];
      #pragma unroll
      for (int ks = 0; ks < 4; ++ks)
        B[ks] = *(const bf16x8*)(wb1 + ((d*CH + k)*CH + ks*32 + lq*8));
      #pragma unroll
      for (int mt = 0; mt <= d; ++mt) {
        const int rowbase = BROW[d] + mt*16;
        f32x4 acc = {0.f, 0.f, 0.f, 0.f};
        #pragma unroll
        for (int ks = 0; ks < 4; ++ks) {
          const bf16x8 a = *(const bf16x8*)&hsh[ks*4 + lq][rowbase + l16][0];
          acc = __builtin_amdgcn_mfma_f32_16x16x32_bf16(a, B[ks], acc, 0, 0, 0);
        }
        #pragma unroll
        for (int i = 0; i < 4; ++i) {
          const int rr   = mt*16 + lq*4 + i;
          const int node = rr & 7, sl = rr >> 3;
          if (sl <= 2*d) {
            const int s = d*d + sl;
            const float vv = acc[i] + ((s == 0) ? b1[k] : 0.f);
            hg[node][s >> 3][k][s & 7] = f2bf(vv);
          }
        }
      }
    }
  }
  // no barrier: hg columns are wave-private

  // ---- Gaunt: to-grid (MFMA) -> square -> from-grid (MFMA); tables hoisted in registers ----
  {
    bf16x8 Ato[6];
    #pragma unroll
    for (int gt = 0; gt < 6; ++gt)
      Ato[gt] = *(const bf16x8*)(toT + (gt*16 + l16)*KPAD + lq*8);
    bf16x8 Afr[2][3];
    #pragma unroll
    for (int mt = 0; mt < 2; ++mt)
      #pragma unroll
      for (int ks = 0; ks < 3; ++ks)
        Afr[mt][ks] = *(const bf16x8*)(frT + (mt*16 + l16)*GPAD + ks*32 + lq*8);

    const int cw = w*16 + l16;
    float wtp[2][4]; int hrow[2][4];
    #pragma unroll
    for (int mt = 0; mt < 2; ++mt)
      #pragma unroll
      for (int i = 0; i < 4; ++i) {
        const int l = mt*16 + lq*4 + i;
        if (l < L2C) {
          const int d = LDEG[l];
          wtp[mt][i]  = w_tp[d*CH + cw];
          hrow[mt][i] = BROW[d] + (l - d*d)*NB;
        } else { wtp[mt][i] = 0.f; hrow[mt][i] = -1; }
      }

    for (int node = 0; node < NB; ++node) {
      const bf16x8 Bh = *(const bf16x8*)&hg[node][lq][cw][0];
      #pragma unroll
      for (int gt = 0; gt < 6; ++gt) {
        f32x4 acc = {0.f, 0.f, 0.f, 0.f};
        acc = __builtin_amdgcn_mfma_f32_16x16x32_bf16(Ato[gt], Bh, acc, 0, 0, 0);
        const int g0 = gt*16 + lq*4;
        short4v sv;
        #pragma unroll
        for (int i = 0; i < 4; ++i) sv[i] = f2bf(acc[i]*acc[i]);
        *(short4v*)&g2[g0 >> 3][cw][g0 & 7] = sv;      // wave-private columns
      }
      #pragma unroll
      for (int mt = 0; mt < 2; ++mt) {
        f32x4 acc = {0.f, 0.f, 0.f, 0.f};
        #pragma unroll
        for (int ks = 0; ks < 3; ++ks) {
          const bf16x8 Bg = *(const bf16x8*)&g2[ks*4 + lq][cw][0];
          acc = __builtin_amdgcn_mfma_f32_16x16x32_bf16(Afr[mt][ks], Bg, acc, 0, 0, 0);
        }
        #pragma unroll
        for (int i = 0; i < 4; ++i)
          if (hrow[mt][i] >= 0)
            hsh[cw >> 3][hrow[mt][i] + node][cw & 7] = f2bf(acc[i] * wtp[mt][i]);
      }
    }
  }
  __syncthreads();   // h now holds Gaunt output; linear2 reads all columns

  // ---- linear2 + bias(l=0) + residual -> out ----
  {
    const int k = w*16 + l16;
    #pragma unroll
    for (int d = 0; d < 5; ++d) {
      bf16x8 B[4];
      #pragma unroll
      for (int ks = 0; ks < 4; ++ks)
        B[ks] = *(const bf16x8*)(wb2 + ((d*CH + k)*CH + ks*32 + lq*8));
      #pragma unroll
      for (int mt = 0; mt <= d; ++mt) {
        const int rowbase = BROW[d] + mt*16;
        f32x4 acc = {0.f, 0.f, 0.f, 0.f};
        #pragma unroll
        for (int ks = 0; ks < 4; ++ks) {
          const bf16x8 a = *(const bf16x8*)&hsh[ks*4 + lq][rowbase + l16][0];
          acc = __builtin_amdgcn_mfma_f32_16x16x32_bf16(a, B[ks], acc, 0, 0, 0);
        }
        #pragma unroll
        for (int i = 0; i < 4; ++i) {
          const int rr   = mt*16 + lq*4 + i;
          const int node = rr & 7, sl = rr >> 3;
          if (sl <= 2*d) {
            const int s = d*d + sl;
            const long base = (n0 + node)*(long)(L2C*CH) + s*CH + k;
            out[base] = acc[i] + ((s == 0) ? b2[k] : 0.f) + x[base];
          }
        }
      }
    }
  }
}

// ---------------- launch ----------------
extern "C" void kernel_launch(void* const* d_in, const int* in_sizes, int n_in,
                              void* d_out, int out_size, void* d_ws, size_t ws_size,
                              hipStream_t stream) {
  const float* x      = (const float*)d_in[0];
  // d_in[1] = batch (unused)
  const float* norm_w = (const float*)d_in[2];
  const float* norm_b = (const float*)d_in[3];
  const float* w1     = (const float*)d_in[4];
  const float* b1     = (const float*)d_in[5];
  const float* w_tp   = (const float*)d_in[6];
  const float* w2     = (const float*)d_in[7];
  const float* b2     = (const float*)d_in[8];
  float* out = (float*)d_out;

  const int N = in_sizes[0] / (L2C*CH);   // 6000

  short* wsS = (short*)d_ws;              // needs ~340 KB
  short* toT = wsS;                       // [96][32]
  short* frT = toT + GPAD*KPAD;           // [32][96]
  short* wb1 = frT + KPAD*GPAD;           // [5][128][128]
  short* wb2 = wb1 + 5*CH*CH;

  build_tables_kernel<<<1, 128, 0, stream>>>(toT, frT);
  convert_w_kernel<<<(5*CH*CH + 255)/256, 256, 0, stream>>>(w1, w2, wb1, wb2);
  eqv3_mfma_kernel<<<N/NB, 512, 0, stream>>>(x, norm_w, norm_b, wb1, b1, w_tp, wb2, b2, toT, frT, out);
}